// Round 1
// baseline (5357.095 us; speedup 1.0000x reference)
//
#include <hip/hip_runtime.h>
#include <cmath>

// CustomRNNCell: h_{t+1} = tanh(h_t @ W_h^T + b_h + x_t @ W_x^T + b_x)
// B=64, T=512, H=I=1024. Output: h_final [64,1024] fp32.
//
// Phase 1: xp[t][b][j] = x @ W_x^T + (b_x + b_h)   (bf16 MFMA GEMM, fp32 out)
// Phase 2 (R5 rewrite): single-round-trip tag-in-band exchange.
//   - 256 blocks x 64 threads (1 wave each): 4 batch-groups x 64 j-waves.
//   - C^T MFMA orientation: C[j,b] = sum_k W[j,k] h[b,k]; A=W (LDS), B=h.
//     Batch rides lane&15 on both producer (C/D col) and consumer (B-frag
//     col) sides -> no LDS transpose.
//   - h exchanged as u32 = (bf16 << 16) | step_tag in a 4-slot ring.
//     Every 8-B unit is stored/loaded with relaxed agent-scope atomics; the
//     low tag of each u64 validates both u32s (u64 store atomicity).
//     Consumers speculatively load, verify tags in registers, retry stale
//     fragments: ONE IF round-trip on the critical path, no flags, no
//     producer drain, no barriers.
//   - Safety: all-gather each step bounds inter-wave skew to <=1 step, so a
//     4-deep ring can never overwrite a live slot (writer of h_{t+4} implies
//     all waves passed t+3; stale readers would need to be at t-3).

#define Bsz 64
#define Tsz 512
#define Hsz 1024

typedef float  f32x4 __attribute__((ext_vector_type(4)));
typedef short  s16x8 __attribute__((ext_vector_type(8)));

__device__ __forceinline__ unsigned short f2bf(float f) {
  unsigned u = __float_as_uint(f);
  u += 0x7fff + ((u >> 16) & 1);   // round-to-nearest-even (finite inputs)
  return (unsigned short)(u >> 16);
}

__device__ __forceinline__ void pack8(unsigned short* d, float4 v0, float4 v1) {
  d[0] = f2bf(v0.x); d[1] = f2bf(v0.y); d[2] = f2bf(v0.z); d[3] = f2bf(v0.w);
  d[4] = f2bf(v1.x); d[5] = f2bf(v1.y); d[6] = f2bf(v1.z); d[7] = f2bf(v1.w);
}

__device__ __forceinline__ float fast_tanh(float x) {
  float e = __expf(2.0f * x);
  return 1.0f - 2.0f / (e + 1.0f);
}

// ---------------- Phase 1: xp GEMM (unchanged, validated) ----------------
__global__ __launch_bounds__(256) void xp_gemm_kernel(
    const float* __restrict__ x, const float* __restrict__ Wx,
    const float* __restrict__ bx, const float* __restrict__ bh,
    float* __restrict__ xp) {
  __shared__ unsigned short Al[64 * 32];
  __shared__ unsigned short Bl[64 * 32];

  const int tid  = threadIdx.x;
  const int w    = tid >> 6;
  const int lane = tid & 63;
  const int m    = lane & 15;
  const int q    = lane >> 4;
  const int row0 = blockIdx.x * 64;   // flattened (b*T + t) row base
  const int col0 = blockIdx.y * 64;   // hidden col base

  f32x4 acc[4];
#pragma unroll
  for (int i = 0; i < 4; ++i) acc[i] = (f32x4){0.f, 0.f, 0.f, 0.f};

  const int sr = tid >> 2;
  const int sc = tid & 3;
  const int sw = sc ^ ((sr >> 1) & 3);

  for (int kt = 0; kt < 32; ++kt) {
    const int k0 = kt * 32 + sc * 8;
    {
      const float* p = x + (size_t)(row0 + sr) * 1024 + k0;
      pack8(&Al[sr * 32 + sw * 8], *(const float4*)p, *(const float4*)(p + 4));
    }
    {
      const float* p = Wx + (size_t)(col0 + sr) * 1024 + k0;
      pack8(&Bl[sr * 32 + sw * 8], *(const float4*)p, *(const float4*)(p + 4));
    }
    __syncthreads();
    const int arow = w * 16 + m;
    s16x8 a = *(const s16x8*)&Al[arow * 32 + ((q ^ ((arow >> 1) & 3)) << 3)];
#pragma unroll
    for (int nt = 0; nt < 4; ++nt) {
      const int nrow = nt * 16 + m;
      s16x8 b = *(const s16x8*)&Bl[nrow * 32 + ((q ^ ((nrow >> 1) & 3)) << 3)];
      acc[nt] = __builtin_amdgcn_mfma_f32_16x16x32_bf16(a, b, acc[nt], 0, 0, 0);
    }
    __syncthreads();
  }

#pragma unroll
  for (int nt = 0; nt < 4; ++nt) {
    const int col  = col0 + nt * 16 + m;
    const float bias = bx[col] + bh[col];
#pragma unroll
    for (int r = 0; r < 4; ++r) {
      const int rowg = row0 + w * 16 + q * 4 + r;  // = b*512 + t
      const int b = rowg >> 9;
      const int t = rowg & 511;
      xp[(size_t)t * (Bsz * Hsz) + b * Hsz + col] = acc[nt][r] + bias;
    }
  }
}

// ---------------- Phase 2: tag-in-band single-RT scan ----------------
// Ring layout (u32 units): slot[4] x group[4] x ( (k>>2)*64 + b*4 + (k&3) ),
// k = hidden index 0..1023, b = batch-local 0..15. As u64:
//   idx = (k>>2)*32 + b*2 + ((k>>1)&1).  Slot stride 32768 u64 (256 KB),
//   group stride 8192 u64 (64 KB). Total ring = 1 MB.
// u32 value = (bf16(h) << 16) | tag, tag = step at which it is consumed.

#define LOADG(D, g)                                                           \
  do {                                                                        \
    _Pragma("unroll")                                                         \
    for (int f_ = 0; f_ < 8; ++f_) {                                          \
      const unsigned long long* fb_ = rbase + ((g) * 8 + f_) * 256;           \
      D[f_ * 4 + 0] = __hip_atomic_load(fb_,      __ATOMIC_RELAXED, __HIP_MEMORY_SCOPE_AGENT); \
      D[f_ * 4 + 1] = __hip_atomic_load(fb_ + 1,  __ATOMIC_RELAXED, __HIP_MEMORY_SCOPE_AGENT); \
      D[f_ * 4 + 2] = __hip_atomic_load(fb_ + 32, __ATOMIC_RELAXED, __HIP_MEMORY_SCOPE_AGENT); \
      D[f_ * 4 + 3] = __hip_atomic_load(fb_ + 33, __ATOMIC_RELAXED, __HIP_MEMORY_SCOPE_AGENT); \
    }                                                                         \
  } while (0)

// u64 store atomicity => low tag validates both u32s of the u64.
#define CHECK4(D, f)                                                          \
  (int)((((unsigned)D[(f) * 4 + 0] & 0xFFFFu) == tg) &                        \
        (((unsigned)D[(f) * 4 + 1] & 0xFFFFu) == tg) &                        \
        (((unsigned)D[(f) * 4 + 2] & 0xFFFFu) == tg) &                        \
        (((unsigned)D[(f) * 4 + 3] & 0xFFFFu) == tg))

#define FIXG(D, g)                                                            \
  do {                                                                        \
    _Pragma("unroll")                                                         \
    for (int f_ = 0; f_ < 8; ++f_) {                                          \
      int ok_ = CHECK4(D, f_);                                                \
      while (!__all(ok_)) {                                                   \
        const unsigned long long* fb_ = rbase + ((g) * 8 + f_) * 256;         \
        D[f_ * 4 + 0] = __hip_atomic_load(fb_,      __ATOMIC_RELAXED, __HIP_MEMORY_SCOPE_AGENT); \
        D[f_ * 4 + 1] = __hip_atomic_load(fb_ + 1,  __ATOMIC_RELAXED, __HIP_MEMORY_SCOPE_AGENT); \
        D[f_ * 4 + 2] = __hip_atomic_load(fb_ + 32, __ATOMIC_RELAXED, __HIP_MEMORY_SCOPE_AGENT); \
        D[f_ * 4 + 3] = __hip_atomic_load(fb_ + 33, __ATOMIC_RELAXED, __HIP_MEMORY_SCOPE_AGENT); \
        ok_ = CHECK4(D, f_);                                                  \
      }                                                                       \
    }                                                                         \
  } while (0)

#define COMPUTEG(D, g)                                                        \
  do {                                                                        \
    _Pragma("unroll")                                                         \
    for (int f_ = 0; f_ < 8; ++f_) {                                          \
      const int kk_ = (g) * 8 + f_;                                           \
      union { unsigned u[4]; s16x8 v; } hb_;                                  \
      hb_.u[0] = __builtin_amdgcn_perm((unsigned)(D[f_ * 4 + 0] >> 32),       \
                                       (unsigned)D[f_ * 4 + 0], 0x07060302u); \
      hb_.u[1] = __builtin_amdgcn_perm((unsigned)(D[f_ * 4 + 1] >> 32),       \
                                       (unsigned)D[f_ * 4 + 1], 0x07060302u); \
      hb_.u[2] = __builtin_amdgcn_perm((unsigned)(D[f_ * 4 + 2] >> 32),       \
                                       (unsigned)D[f_ * 4 + 2], 0x07060302u); \
      hb_.u[3] = __builtin_amdgcn_perm((unsigned)(D[f_ * 4 + 3] >> 32),       \
                                       (unsigned)D[f_ * 4 + 3], 0x07060302u); \
      s16x8 wf_ = *(const s16x8*)&Wl[m * 1024 + (((kk_ * 4 + q) ^ (m & 7)) << 3)]; \
      f32x4& ac_ = ((kk_ & 3) == 0) ? acc0 : ((kk_ & 3) == 1) ? acc1          \
                  : ((kk_ & 3) == 2) ? acc2 : acc3;                           \
      ac_ = __builtin_amdgcn_mfma_f32_16x16x32_bf16(wf_, hb_.v, ac_, 0, 0, 0);\
    }                                                                         \
  } while (0)

__global__ __launch_bounds__(64) void rnn_scan_kernel(
    const float* __restrict__ Wh, const float* __restrict__ xp,
    float* __restrict__ out, unsigned long long* __restrict__ ring) {
  __shared__ unsigned short Wl[16 * 1024];  // 32 KB: W rows j0..j0+15, bf16

  const int lane = threadIdx.x & 63;
  const int m    = lane & 15;       // batch-local (B-frag col / C col)
  const int q    = lane >> 4;
  const int gb   = blockIdx.x >> 6; // 0..3  batch group
  const int gj   = blockIdx.x & 63; // 0..63 j-wave (16 output cols each)
  const int j0   = gj * 16;
  const int rb   = gb * 16;

  // W_h rows j0..j0+15 -> LDS bf16, chunk-swizzled (c ^= row&7) for
  // conflict-balanced ds_read_b128 (same scheme as validated R4 kernel).
  for (int i = 0; i < 32; ++i) {
    const int jr = i >> 1;
    const int c  = (i & 1) * 64 + lane;     // 16-B chunk index 0..127
    const float* p = Wh + (size_t)(j0 + jr) * 1024 + c * 8;
    pack8(&Wl[jr * 1024 + ((c ^ (jr & 7)) << 3)],
          *(const float4*)p, *(const float4*)(p + 4));
  }
  __syncthreads();

  const size_t grpoff = (size_t)gb * 8192;        // u64 units
  const int    ldoff  = q * 64 + m * 2;           // consumer per-lane base
  const int    stoff  = (gj * 4 + q) * 32 + m * 2;// producer per-lane base

  for (int t = 0; t < Tsz; ++t) {
    // xp_t for (b = rb+m, j = j0+q*4+r) — aligned float4, line-coalesced
    const float4 xv = *(const float4*)(
        xp + (size_t)t * (Bsz * Hsz) + (size_t)(rb + m) * Hsz + j0 + q * 4);

    f32x4 acc0 = (f32x4){0.f, 0.f, 0.f, 0.f};
    f32x4 acc1 = (f32x4){0.f, 0.f, 0.f, 0.f};
    f32x4 acc2 = (f32x4){0.f, 0.f, 0.f, 0.f};
    f32x4 acc3 = (f32x4){0.f, 0.f, 0.f, 0.f};

    if (t > 0) {
      const unsigned tg = (unsigned)t;
      const unsigned long long* rbase =
          ring + (size_t)(t & 3) * 32768 + grpoff + ldoff;

      unsigned long long A[32], B[32];
      // 2-deep pipeline: group g+1's loads are in flight while group g is
      // validated and fed to MFMA. Branches (retry) only gate re-loads.
      LOADG(A, 0);
      LOADG(B, 1);
      FIXG(A, 0); COMPUTEG(A, 0);
      LOADG(A, 2);
      FIXG(B, 1); COMPUTEG(B, 1);
      LOADG(B, 3);
      FIXG(A, 2); COMPUTEG(A, 2);
      FIXG(B, 3); COMPUTEG(B, 3);
    }

    const f32x4 accs = (acc0 + acc1) + (acc2 + acc3);
    float hv[4];
#pragma unroll
    for (int r = 0; r < 4; ++r) hv[r] = fast_tanh(accs[r] + xv.x * 0.f + ((const float*)&xv)[r]);

    if (t == Tsz - 1) {
      *(float4*)&out[(size_t)(rb + m) * Hsz + j0 + q * 4] =
          make_float4(hv[0], hv[1], hv[2], hv[3]);
    } else {
      // tag for consumers at step t+1
      const unsigned tg1 = (unsigned)(t + 1);
      const unsigned long long s0 =
          (unsigned long long)(tg1 | ((unsigned)f2bf(hv[0]) << 16)) |
          ((unsigned long long)(tg1 | ((unsigned)f2bf(hv[1]) << 16)) << 32);
      const unsigned long long s1 =
          (unsigned long long)(tg1 | ((unsigned)f2bf(hv[2]) << 16)) |
          ((unsigned long long)(tg1 | ((unsigned)f2bf(hv[3]) << 16)) << 32);
      unsigned long long* wb =
          ring + (size_t)((t + 1) & 3) * 32768 + grpoff + stoff;
      __hip_atomic_store(wb,     s0, __ATOMIC_RELAXED, __HIP_MEMORY_SCOPE_AGENT);
      __hip_atomic_store(wb + 1, s1, __ATOMIC_RELAXED, __HIP_MEMORY_SCOPE_AGENT);
    }
  }
}

extern "C" void kernel_launch(void* const* d_in, const int* in_sizes, int n_in,
                              void* d_out, int out_size, void* d_ws, size_t ws_size,
                              hipStream_t stream) {
  (void)in_sizes; (void)n_in; (void)out_size; (void)ws_size;
  const float* x  = (const float*)d_in[0];  // [64,512,1024]
  const float* Wh = (const float*)d_in[1];  // [1024,1024]
  const float* bh = (const float*)d_in[2];  // [1024]
  const float* Wx = (const float*)d_in[3];  // [1024,1024]
  const float* bx = (const float*)d_in[4];  // [1024]
  float* out = (float*)d_out;               // [64,1024]

  char* ws = (char*)d_ws;
  unsigned long long* ring = (unsigned long long*)ws;   // 1 MB, 4-slot ring
  float*              xp   = (float*)(ws + (1 << 20));  // 128 MB

  // ring tags must start < 1 (step-1 consumers wait on tag==1)
  hipMemsetAsync(d_ws, 0, 1 << 20, stream);

  dim3 g1(Bsz * Tsz / 64, Hsz / 64);
  xp_gemm_kernel<<<g1, dim3(256), 0, stream>>>(x, Wx, bx, bh, xp);
  rnn_scan_kernel<<<dim3(256), dim3(64), 0, stream>>>(Wh, xp, out, ring);
}

// Round 2
// 1761.476 us; speedup vs baseline: 3.0413x; 3.0413x over previous
//
#include <hip/hip_runtime.h>
#include <cmath>

// CustomRNNCell: h_{t+1} = tanh(h_t @ W_h^T + b_h + x_t @ W_x^T + b_x)
// B=64, T=512, H=I=1024. Output: h_final [64,1024] fp32.
//
// Phase 1: xp[t][b][j] = x @ W_x^T + (b_x + b_h)   (bf16 MFMA GEMM, fp32 out)
// Phase 2 (R6): flag protocol (R4, proven) x C^T layout (R5, validated).
//   - 256 blocks x 64 threads (1 wave): 4 batch-groups x 64 j-waves (16 j).
//   - C^T MFMA: C[j,b] = sum_k W[j,k] h[b,k]; A=W (LDS), B=h. Producer C/D
//     lane order == consumer B-frag order -> h published as ONE packed u64
//     per lane, no LDS transpose, no barrier, no perm.
//   - Exchange: bf16 h in a 2-slot ring; per-wave flag published after
//     s_waitcnt vmcnt(0) (store drained to coherence point). Consumer polls
//     all 64 producer flags to FULL readiness (single __all ballot; no
//     mid-loop polls -> no in-order-vmcnt drains of in-flight data loads),
//     then bulk-issues all 64 u64 data loads, then 32 ds_read+MFMA.
//   - 2-slot safety: write of h_{t+1} (slot (t+1)&1) happens only after all
//     flags >= t, i.e. every wave stored h_t, i.e. finished reading h_{t-1}
//     from the slot being overwritten.

#define Bsz 64
#define Tsz 512
#define Hsz 1024

typedef float  f32x4 __attribute__((ext_vector_type(4)));
typedef short  s16x8 __attribute__((ext_vector_type(8)));

__device__ __forceinline__ unsigned short f2bf(float f) {
  unsigned u = __float_as_uint(f);
  u += 0x7fff + ((u >> 16) & 1);   // round-to-nearest-even (finite inputs)
  return (unsigned short)(u >> 16);
}

__device__ __forceinline__ void pack8(unsigned short* d, float4 v0, float4 v1) {
  d[0] = f2bf(v0.x); d[1] = f2bf(v0.y); d[2] = f2bf(v0.z); d[3] = f2bf(v0.w);
  d[4] = f2bf(v1.x); d[5] = f2bf(v1.y); d[6] = f2bf(v1.z); d[7] = f2bf(v1.w);
}

__device__ __forceinline__ float fast_tanh(float x) {
  float e = __expf(2.0f * x);
  return 1.0f - 2.0f / (e + 1.0f);
}

// ---------------- Phase 1: xp GEMM (unchanged, validated) ----------------
__global__ __launch_bounds__(256) void xp_gemm_kernel(
    const float* __restrict__ x, const float* __restrict__ Wx,
    const float* __restrict__ bx, const float* __restrict__ bh,
    float* __restrict__ xp) {
  __shared__ unsigned short Al[64 * 32];
  __shared__ unsigned short Bl[64 * 32];

  const int tid  = threadIdx.x;
  const int w    = tid >> 6;
  const int lane = tid & 63;
  const int m    = lane & 15;
  const int q    = lane >> 4;
  const int row0 = blockIdx.x * 64;   // flattened (b*T + t) row base
  const int col0 = blockIdx.y * 64;   // hidden col base

  f32x4 acc[4];
#pragma unroll
  for (int i = 0; i < 4; ++i) acc[i] = (f32x4){0.f, 0.f, 0.f, 0.f};

  const int sr = tid >> 2;
  const int sc = tid & 3;
  const int sw = sc ^ ((sr >> 1) & 3);

  for (int kt = 0; kt < 32; ++kt) {
    const int k0 = kt * 32 + sc * 8;
    {
      const float* p = x + (size_t)(row0 + sr) * 1024 + k0;
      pack8(&Al[sr * 32 + sw * 8], *(const float4*)p, *(const float4*)(p + 4));
    }
    {
      const float* p = Wx + (size_t)(col0 + sr) * 1024 + k0;
      pack8(&Bl[sr * 32 + sw * 8], *(const float4*)p, *(const float4*)(p + 4));
    }
    __syncthreads();
    const int arow = w * 16 + m;
    s16x8 a = *(const s16x8*)&Al[arow * 32 + ((q ^ ((arow >> 1) & 3)) << 3)];
#pragma unroll
    for (int nt = 0; nt < 4; ++nt) {
      const int nrow = nt * 16 + m;
      s16x8 b = *(const s16x8*)&Bl[nrow * 32 + ((q ^ ((nrow >> 1) & 3)) << 3)];
      acc[nt] = __builtin_amdgcn_mfma_f32_16x16x32_bf16(a, b, acc[nt], 0, 0, 0);
    }
    __syncthreads();
  }

#pragma unroll
  for (int nt = 0; nt < 4; ++nt) {
    const int col  = col0 + nt * 16 + m;
    const float bias = bx[col] + bh[col];
#pragma unroll
    for (int r = 0; r < 4; ++r) {
      const int rowg = row0 + w * 16 + q * 4 + r;  // = b*512 + t
      const int b = rowg >> 9;
      const int t = rowg & 511;
      xp[(size_t)t * (Bsz * Hsz) + b * Hsz + col] = acc[nt][r] + bias;
    }
  }
}

// ---------------- Phase 2: flag-gated C^T scan ----------------
// Ring (bf16 units): slot[2] x group[4] x [(k>>3)*128 + b*8 + (k&7)],
// k = hidden 0..1023, b = batch-local 0..15.
// As u64: idx = (k>>3)*32 + b*2 + ((k>>2)&1).
// Slot stride 16384 u64 (128 KB), group stride 4096 u64 (32 KB).
// Consumer fragment kk (k-window kk*32..+31), lane(m,q):
//   u64 idx = kk*128 + q*32 + m*2 (+1)  -> contiguous 16 B = B-frag s16x8.
// Producer wave gj, lane(m,q) holds C rows q*4+r (j = gj*16+q*4+r), col m:
//   u64 idx = (gj*2+(q>>1))*32 + m*2 + (q&1), packed hv[0..3] low->high.

__global__ __launch_bounds__(64, 1) void rnn_scan_kernel(
    const float* __restrict__ Wh, const float* __restrict__ xp,
    float* __restrict__ out,
    unsigned long long* __restrict__ ring, unsigned* __restrict__ flags) {
  __shared__ unsigned short Wl[16 * 1024];  // 32 KB: W rows j0..j0+15, bf16

  const int lane = threadIdx.x & 63;
  const int m    = lane & 15;       // batch-local (B-frag col / C col)
  const int q    = lane >> 4;
  const int gb   = blockIdx.x >> 6; // 0..3  batch group
  const int gj   = blockIdx.x & 63; // 0..63 j-wave (16 output cols each)
  const int j0   = gj * 16;
  const int rb   = gb * 16;

  // W_h rows j0..j0+15 -> LDS bf16, chunk-swizzled (c ^= row&7); validated.
  for (int i = 0; i < 32; ++i) {
    const int jr = i >> 1;
    const int c  = (i & 1) * 64 + lane;     // 16-B chunk index 0..127
    const float* p = Wh + (size_t)(j0 + jr) * 1024 + c * 8;
    pack8(&Wl[jr * 1024 + ((c ^ (jr & 7)) << 3)],
          *(const float4*)p, *(const float4*)(p + 4));
  }
  __syncthreads();

  unsigned* grpflags = flags + gb * 1024;          // 64 flags x 64-B stride
  unsigned* myflag   = grpflags + gj * 16;
  const unsigned* pollflag = grpflags + lane * 16; // lane l polls producer l

  unsigned long long* const grp = ring + (size_t)gb * 4096;
  const int cons_off = q * 32 + m * 2;
  const int prod_off = (gj * 2 + (q >> 1)) * 32 + m * 2 + (q & 1);

  for (int t = 0; t < Tsz; ++t) {
    // xp_t for (b = rb+m, j = j0+q*4+r) — independent of recurrence
    const float4 xv = *(const float4*)(
        xp + (size_t)t * (Bsz * Hsz) + (size_t)(rb + m) * Hsz + j0 + q * 4);
    const float* xf = (const float*)&xv;

    f32x4 acc0 = (f32x4){0.f, 0.f, 0.f, 0.f};
    f32x4 acc1 = (f32x4){0.f, 0.f, 0.f, 0.f};
    f32x4 acc2 = (f32x4){0.f, 0.f, 0.f, 0.f};
    f32x4 acc3 = (f32x4){0.f, 0.f, 0.f, 0.f};

    if (t > 0) {
      const unsigned tg = (unsigned)t;
      // Poll to full readiness: one flag per lane, wave-wide ballot.
      unsigned v = __hip_atomic_load(pollflag, __ATOMIC_RELAXED,
                                     __HIP_MEMORY_SCOPE_AGENT);
      while (!__all((int)(v >= tg))) {
        __builtin_amdgcn_s_sleep(1);
        v = __hip_atomic_load(pollflag, __ATOMIC_RELAXED,
                              __HIP_MEMORY_SCOPE_AGENT);
      }

      // Bulk-issue all data loads (contiguous u64 pairs per fragment).
      const unsigned long long* rbase =
          grp + (size_t)(t & 1) * 16384 + cons_off;
      unsigned long long d[64];
#pragma unroll
      for (int kk = 0; kk < 32; ++kk) {
        d[2 * kk]     = __hip_atomic_load(rbase + kk * 128,     __ATOMIC_RELAXED,
                                          __HIP_MEMORY_SCOPE_AGENT);
        d[2 * kk + 1] = __hip_atomic_load(rbase + kk * 128 + 1, __ATOMIC_RELAXED,
                                          __HIP_MEMORY_SCOPE_AGENT);
      }

#pragma unroll
      for (int kk = 0; kk < 32; ++kk) {
        union { unsigned long long u[2]; s16x8 v; } hb;
        hb.u[0] = d[2 * kk];
        hb.u[1] = d[2 * kk + 1];
        s16x8 wf = *(const s16x8*)&Wl[m * 1024 + (((kk * 4 + q) ^ (m & 7)) << 3)];
        f32x4& ac = ((kk & 3) == 0) ? acc0 : ((kk & 3) == 1) ? acc1
                   : ((kk & 3) == 2) ? acc2 : acc3;
        ac = __builtin_amdgcn_mfma_f32_16x16x32_bf16(wf, hb.v, ac, 0, 0, 0);
      }
    }

    const f32x4 accs = (acc0 + acc1) + (acc2 + acc3);
    float hv[4];
#pragma unroll
    for (int r = 0; r < 4; ++r) hv[r] = fast_tanh(accs[r] + xf[r]);

    if (t == Tsz - 1) {
      *(float4*)&out[(size_t)(rb + m) * Hsz + j0 + q * 4] =
          make_float4(hv[0], hv[1], hv[2], hv[3]);
    } else {
      const unsigned long long s =
          (unsigned long long)f2bf(hv[0])        |
          ((unsigned long long)f2bf(hv[1]) << 16) |
          ((unsigned long long)f2bf(hv[2]) << 32) |
          ((unsigned long long)f2bf(hv[3]) << 48);
      unsigned long long* wb =
          grp + (size_t)((t + 1) & 1) * 16384 + prod_off;
      __hip_atomic_store(wb, s, __ATOMIC_RELAXED, __HIP_MEMORY_SCOPE_AGENT);
      // Drain own store to the coherence point, then publish readiness.
      __asm__ __volatile__("s_waitcnt vmcnt(0)" ::: "memory");
      if (lane == 0)
        __hip_atomic_store(myflag, (unsigned)(t + 1), __ATOMIC_RELAXED,
                           __HIP_MEMORY_SCOPE_AGENT);
    }
  }
}

extern "C" void kernel_launch(void* const* d_in, const int* in_sizes, int n_in,
                              void* d_out, int out_size, void* d_ws, size_t ws_size,
                              hipStream_t stream) {
  (void)in_sizes; (void)n_in; (void)out_size; (void)ws_size;
  const float* x  = (const float*)d_in[0];  // [64,512,1024]
  const float* Wh = (const float*)d_in[1];  // [1024,1024]
  const float* bh = (const float*)d_in[2];  // [1024]
  const float* Wx = (const float*)d_in[3];  // [1024,1024]
  const float* bx = (const float*)d_in[4];  // [1024]
  float* out = (float*)d_out;               // [64,1024]

  char* ws = (char*)d_ws;
  unsigned*           flags = (unsigned*)ws;                    // 16 KB
  unsigned long long* ring  = (unsigned long long*)(ws + 65536);// 256 KB
  float*              xp    = (float*)(ws + (1 << 20));         // 128 MB

  // only flags need zeroing (step 0 reads no h buffer)
  hipMemsetAsync(d_ws, 0, 16384, stream);

  dim3 g1(Bsz * Tsz / 64, Hsz / 64);
  xp_gemm_kernel<<<g1, dim3(256), 0, stream>>>(x, Wx, bx, bh, xp);
  rnn_scan_kernel<<<dim3(256), dim3(64), 0, stream>>>(Wh, xp, out, ring, flags);
}